// Round 11
// baseline (427.618 us; speedup 1.0000x reference)
//
#include <hip/hip_runtime.h>
#include <math.h>

#define NN   131072
#define CN   128
#define BN   64
#define NPGN 2048
#define MN   64
#define EN   1048576

typedef unsigned short u16;
typedef unsigned int   u32;
typedef __attribute__((ext_vector_type(8))) short short8;
typedef __attribute__((ext_vector_type(4))) float f32x4;

__device__ __forceinline__ float bf2f(u16 u){ return __uint_as_float(((u32)u)<<16); }
__device__ __forceinline__ u16 f2bf(float f){
  u32 x = __float_as_uint(f);
  return (u16)((x + 0x7fffu + ((x>>16)&1u)) >> 16);
}

// ---------------- graph scans ----------------
__global__ void k_scan1(const int* __restrict__ deg, int* __restrict__ rowst, int* __restrict__ bsum){
  __shared__ int s[512];
  const int t = threadIdx.x;
  const int i = blockIdx.x*512 + t;
  int v = deg[i];
  s[t] = v;
  __syncthreads();
  for (int off=1; off<512; off<<=1){
    int a = (t>=off) ? s[t-off] : 0;
    __syncthreads();
    s[t] += a;
    __syncthreads();
  }
  rowst[i] = s[t] - v;
  if (t==511) bsum[blockIdx.x] = s[511];
}

// merged scan2+scan3: each block adds sum(bsum[0 .. bid/2)) to its rowst slice
__global__ void k_scan23(int* __restrict__ rowst, const int* __restrict__ bsum){
  __shared__ int sred[4];
  const int t = threadIdx.x;
  const int gidx = blockIdx.x >> 1;      // all i in this block share i>>9 == bid>>1
  int v = (t < gidx) ? bsum[t] : 0;
  #pragma unroll
  for (int d=1; d<64; d<<=1) v += __shfl_xor(v, d);
  if ((t&63)==0) sred[t>>6] = v;
  __syncthreads();
  int tot = sred[0]+sred[1]+sred[2]+sred[3];
  int i = blockIdx.x*256 + t;
  rowst[i] += tot;
}

// ---------------- front: prep_h + prep_U + prepw + prepWT + count (independent) ----------------
__global__ __launch_bounds__(256) void k_front(
    const float* __restrict__ h, u16* __restrict__ h16, u16* __restrict__ ht16,
    const float* __restrict__ U, u16* __restrict__ U16, u16* __restrict__ Ut16,
    const float* __restrict__ lin_w, u16* __restrict__ wsw,
    const float* __restrict__ W, u16* __restrict__ WT16,
    const int* __restrict__ dst, int* __restrict__ deg){
  __shared__ u16 stu[CN*72];   // 18.4 KB union
  const int t = threadIdx.x;
  const int bid = blockIdx.x;

  if (bid < 2048){
    // ---- prep_h: tile = 64 n-rows x 128 c ----
    const int b = bid >> 5;
    const int n0 = (bid & 31)*64;
    const float* srcb = h + ((size_t)b*NPGN + n0)*CN;
    u16* natb = h16 + ((size_t)b*NPGN + n0)*CN;
    #pragma unroll
    for (int j=0;j<8;++j){
      int fidx = (j*256+t)*4;
      int r = fidx>>7, c = fidx&127;
      float4 v = *(const float4*)(srcb + fidx);
      u16 q0=f2bf(v.x), q1=f2bf(v.y), q2=f2bf(v.z), q3=f2bf(v.w);
      ushort4 nv; nv.x=q0; nv.y=q1; nv.z=q2; nv.w=q3;
      *(ushort4*)(natb + fidx) = nv;
      stu[(c+0)*72 + r] = q0; stu[(c+1)*72 + r] = q1;
      stu[(c+2)*72 + r] = q2; stu[(c+3)*72 + r] = q3;
    }
    __syncthreads();
    #pragma unroll
    for (int j=0;j<4;++j){
      int oidx = (j*256+t)*8;
      int c = oidx>>6, nn = oidx&63;
      uint4 v = *(const uint4*)&stu[c*72 + nn];
      *(uint4*)(ht16 + ((size_t)b*CN + c)*NPGN + n0 + nn) = v;
    }
  } else if (bid < 3072){
    // ---- prep_U: tile = 128 n-rows x 64 m ----
    const int ub = bid - 2048;
    const int b = ub >> 4;
    const int n0 = (ub & 15)*128;
    const float* srcb = U + ((size_t)b*NPGN + n0)*MN;
    u16* natb = U16 + ((size_t)b*NPGN + n0)*MN;
    #pragma unroll
    for (int j=0;j<8;++j){
      int fidx = (j*256+t)*4;
      int r = fidx>>6, mm = fidx&63;
      float4 v = *(const float4*)(srcb + fidx);
      u16 q0=f2bf(v.x), q1=f2bf(v.y), q2=f2bf(v.z), q3=f2bf(v.w);
      ushort4 nv; nv.x=q0; nv.y=q1; nv.z=q2; nv.w=q3;
      *(ushort4*)(natb + fidx) = nv;
      stu[(mm+0)*136 + r] = q0; stu[(mm+1)*136 + r] = q1;
      stu[(mm+2)*136 + r] = q2; stu[(mm+3)*136 + r] = q3;
    }
    __syncthreads();
    #pragma unroll
    for (int j=0;j<4;++j){
      int oidx = (j*256+t)*8;
      int mm = oidx>>7, nn = oidx&127;
      uint4 v = *(const uint4*)&stu[mm*136 + nn];
      *(uint4*)(Ut16 + ((size_t)b*MN + mm)*NPGN + n0 + nn) = v;
    }
  } else if (bid < 3080){
    // ---- prepw: B-fragment-swizzled bf16 lin_w ----
    int tid = (bid - 3072)*256 + t;   // 2048 total
    int g = tid >> 6, L = tid & 63;
    int ct = g >> 2, ks = g & 3;
    int o = L & 15, q = L >> 4;
    const float* srcp = lin_w + (ct*16+o)*CN + ks*32 + q*8;
    u16 tmp[8];
    #pragma unroll
    for (int j=0;j<8;++j) tmp[j] = f2bf(srcp[j]);
    *(uint4*)(wsw + (size_t)tid*8) = *(const uint4*)tmp;
  } else if (bid < 3208){
    // ---- prepWT half-tile: W[m][c][o] -> WT16[m][o][c], c-half per block ----
    const int mb = bid - 3080;         // 0..127
    const int m = mb >> 1, c0 = (mb & 1)*64;
    const float* Wm = W + (size_t)m*CN*CN + (size_t)c0*CN;
    #pragma unroll
    for (int it=0; it<8; ++it){
      int flat = (it*256 + t)*4;       // over 64c x 128o
      int c = flat >> 7, o = flat & 127;
      float4 v = *(const float4*)(Wm + flat);
      stu[(o+0)*68 + c] = f2bf(v.x);
      stu[(o+1)*68 + c] = f2bf(v.y);
      stu[(o+2)*68 + c] = f2bf(v.z);
      stu[(o+3)*68 + c] = f2bf(v.w);
    }
    __syncthreads();
    u16* dstm = WT16 + (size_t)m*CN*CN + c0;
    #pragma unroll
    for (int it=0; it<4; ++it){
      int oidx = (it*256 + t)*8;       // over 128o x 64c
      int o = oidx >> 6, cc = oidx & 63;
      uint4 v = *(const uint4*)&stu[o*68 + cc];
      *(uint4*)(dstm + (size_t)o*CN + cc) = v;
    }
  } else {
    // ---- count ----
    int e = (bid - 3208)*256 + t;
    atomicAdd(&deg[dst[e]], 1);
  }
}

// ---------------- mid: h_hat MFMA partials + csr fill (independent) ----------------
__global__ __launch_bounds__(256) void k_mid(
    const u16* __restrict__ Ut16, const u16* __restrict__ ht16, float* __restrict__ hp,
    const int* __restrict__ src, const int* __restrict__ dst,
    const int* __restrict__ rowst, int* __restrict__ cursor, int* __restrict__ csr){
  const int bid = blockIdx.x;
  if (bid < 1024){
    // hhat: hp[q][b][m][c], K-chunk 256, c-half per block
    const int t = threadIdx.x;
    const int L = t & 63, w = t >> 6;
    const int b  = bid >> 4;
    const int q  = (bid >> 1) & 7;
    const int ch = bid & 1;
    const int lo = L & 15, qd = (L >> 4) << 3;
    f32x4 acc[4] = {};
    const u16* Arow  = Ut16 + ((size_t)(b*MN + w*16 + lo))*NPGN + q*256 + qd;
    const u16* Bbase = ht16 + ((size_t)(b*CN + ch*64 + lo))*NPGN + q*256 + qd;
    #pragma unroll
    for (int ks=0; ks<8; ++ks){
      short8 af = *(const short8*)(Arow + ks*32);
      #pragma unroll
      for (int ct=0; ct<4; ++ct){
        short8 bf = *(const short8*)(Bbase + (size_t)ct*16*NPGN + ks*32);
        acc[ct] = __builtin_amdgcn_mfma_f32_16x16x32_bf16(af, bf, acc[ct], 0, 0, 0);
      }
    }
    const int rb = w*16 + ((L>>4)<<2);
    float* dstb = hp + ((size_t)q*BN + b)*MN*CN;
    #pragma unroll
    for (int ct=0; ct<4; ++ct)
      #pragma unroll
      for (int r=0; r<4; ++r)
        dstb[(size_t)(rb+r)*CN + ch*64 + ct*16 + lo] = acc[ct][r];
  } else {
    // fill csr
    int e = (bid - 1024)*256 + threadIdx.x;
    int d = dst[e];
    int p = atomicAdd(&cursor[d], 1);
    csr[rowst[d] + p] = src[e];
  }
}

// ---------------- out_hat (MFMA): ohatT[b][o][m] = bf16( sum_c hh[b,c]*W[m,c,o] ) ----------------
__global__ __launch_bounds__(256) void k_ohat(const float* __restrict__ hp,
                                              const u16* __restrict__ WT16,
                                              u16* __restrict__ ohatT){
  __shared__ u16 shHi[16*132];   // 4.2 KB
  __shared__ u16 shLo[16*132];   // 4.2 KB
  const int t = threadIdx.x;
  const int m  = blockIdx.x >> 2;
  const int bq = blockIdx.x & 3;       // b-quarter: rows bq*16 .. bq*16+15

  {
    const int bl = t >> 4;             // 0..15
    const int c0 = (t & 15) * 8;       // 8 channels
    const size_t S = (size_t)BN*MN*CN;
    const float* base = hp + ((size_t)(bq*16 + bl)*MN + m)*CN + c0;
    float a[8] = {0,0,0,0,0,0,0,0};
    #pragma unroll
    for (int q=0; q<8; ++q){
      float4 v0 = *(const float4*)(base + q*S);
      float4 v1 = *(const float4*)(base + q*S + 4);
      a[0]+=v0.x; a[1]+=v0.y; a[2]+=v0.z; a[3]+=v0.w;
      a[4]+=v1.x; a[5]+=v1.y; a[6]+=v1.z; a[7]+=v1.w;
    }
    u16 hi[8], lo[8];
    #pragma unroll
    for (int j=0;j<8;++j){
      hi[j] = f2bf(a[j]);
      lo[j] = f2bf(a[j] - bf2f(hi[j]));
    }
    *(uint4*)&shHi[bl*132 + c0] = *(const uint4*)hi;
    *(uint4*)&shLo[bl*132 + c0] = *(const uint4*)lo;
  }
  __syncthreads();

  const int L = t & 63, w = t >> 6;
  const int lo16 = L & 15, qd = (L >> 4) << 3;
  const u16* WTm = WT16 + (size_t)m*CN*CN;
  f32x4 acc[2] = {};
  #pragma unroll
  for (int ks=0; ks<4; ++ks){
    short8 ah = *(const short8*)&shHi[lo16*132 + ks*32 + qd];
    short8 al = *(const short8*)&shLo[lo16*132 + ks*32 + qd];
    #pragma unroll
    for (int ot=0; ot<2; ++ot){
      short8 bf = *(const short8*)(WTm + (size_t)(w*32 + ot*16 + lo16)*CN + ks*32 + qd);
      acc[ot] = __builtin_amdgcn_mfma_f32_16x16x32_bf16(ah, bf, acc[ot], 0, 0, 0);
      acc[ot] = __builtin_amdgcn_mfma_f32_16x16x32_bf16(al, bf, acc[ot], 0, 0, 0);
    }
  }
  const int rb = (L>>4)<<2;
  #pragma unroll
  for (int ot=0; ot<2; ++ot){
    #pragma unroll
    for (int r=0; r<4; ++r){
      int b = bq*16 + rb + r;
      int o = w*32 + ot*16 + lo16;
      ohatT[((size_t)b*CN + o)*MN + m] = f2bf(acc[ot][r]);
    }
  }
}

// ---------------- fused: gather-mean + (local+spec) MFMA + LN + GELU ----------------
__device__ __forceinline__ void unp_add(float* a, uint4 p){
  a[0]+=__uint_as_float(p.x<<16); a[1]+=__uint_as_float(p.x&0xffff0000u);
  a[2]+=__uint_as_float(p.y<<16); a[3]+=__uint_as_float(p.y&0xffff0000u);
  a[4]+=__uint_as_float(p.z<<16); a[5]+=__uint_as_float(p.z&0xffff0000u);
  a[6]+=__uint_as_float(p.w<<16); a[7]+=__uint_as_float(p.w&0xffff0000u);
}

__global__ __launch_bounds__(256,8) void k_localep(
    const u16* __restrict__ h16, const u16* __restrict__ U16,
    const u16* __restrict__ ohatT, const u16* __restrict__ wsw,
    const int* __restrict__ rowst, const int* __restrict__ deg, const int* __restrict__ csr,
    const float* __restrict__ lin_b, const float* __restrict__ ln_g,
    const float* __restrict__ ln_beta, float* __restrict__ out){
  __shared__ u16 sv[32*136];     // 8.7 KB  mean-neighbor rows (bf16, pitch 136)
  __shared__ u16 sx16[32*132];   // 8.4 KB  local+spec result (bf16)
  const int t = threadIdx.x;
  const int w = t>>6, lane = t&63;
  const size_t n0 = (size_t)blockIdx.x*32;

  // Phase A (R8-validated, 90.6us): software-pipelined, manually-unrolled, named
  // scalars only. idx(p+1) loads issue while rows(p) are in flight / unpacking.
  // R11: bound (256,8) — current codegen uses 48 VGPR <= 64-cap, so residency
  // rises 5->8 blocks/CU with identical per-wave ILP.
  {
    const int g   = lane >> 4;    // edge slot 0..3
    const int c16 = lane & 15;    // channel group: channels c16*8 .. c16*8+7
    const u16* hcol = h16 + c16*8;
    const int nb = (int)n0 + w;

#define LOAD_IDX(P, NA, NB) \
    const int rsA##P = rowst[NA], dgA##P = deg[NA]; \
    const int rsB##P = rowst[NB], dgB##P = deg[NB]; \
    const int eA##P = rsA##P + g, eB##P = rsB##P + g; \
    const int reA##P = rsA##P + dgA##P, reB##P = rsB##P + dgB##P; \
    const int jA##P##_0 = csr[min(eA##P     , EN-1)]; \
    const int jA##P##_1 = csr[min(eA##P +  4, EN-1)]; \
    const int jA##P##_2 = csr[min(eA##P +  8, EN-1)]; \
    const int jA##P##_3 = csr[min(eA##P + 12, EN-1)]; \
    const int jB##P##_0 = csr[min(eB##P     , EN-1)]; \
    const int jB##P##_1 = csr[min(eB##P +  4, EN-1)]; \
    const int jB##P##_2 = csr[min(eB##P +  8, EN-1)]; \
    const int jB##P##_3 = csr[min(eB##P + 12, EN-1)];

#define LOAD_ROWS(P) \
    const uint4 qA##P##_0 = *(const uint4*)(hcol + (size_t)((eA##P      < reA##P) ? jA##P##_0 : NN)*CN); \
    const uint4 qA##P##_1 = *(const uint4*)(hcol + (size_t)((eA##P +  4 < reA##P) ? jA##P##_1 : NN)*CN); \
    const uint4 qA##P##_2 = *(const uint4*)(hcol + (size_t)((eA##P +  8 < reA##P) ? jA##P##_2 : NN)*CN); \
    const uint4 qA##P##_3 = *(const uint4*)(hcol + (size_t)((eA##P + 12 < reA##P) ? jA##P##_3 : NN)*CN); \
    const uint4 qB##P##_0 = *(const uint4*)(hcol + (size_t)((eB##P      < reB##P) ? jB##P##_0 : NN)*CN); \
    const uint4 qB##P##_1 = *(const uint4*)(hcol + (size_t)((eB##P +  4 < reB##P) ? jB##P##_1 : NN)*CN); \
    const uint4 qB##P##_2 = *(const uint4*)(hcol + (size_t)((eB##P +  8 < reB##P) ? jB##P##_2 : NN)*CN); \
    const uint4 qB##P##_3 = *(const uint4*)(hcol + (size_t)((eB##P + 12 < reB##P) ? jB##P##_3 : NN)*CN);

#define FINISH(P, IA, IB) \
    { \
      float accA[8]={0,0,0,0,0,0,0,0}, accB[8]={0,0,0,0,0,0,0,0}; \
      unp_add(accA,qA##P##_0); unp_add(accA,qA##P##_1); unp_add(accA,qA##P##_2); unp_add(accA,qA##P##_3); \
      unp_add(accB,qB##P##_0); unp_add(accB,qB##P##_1); unp_add(accB,qB##P##_2); unp_add(accB,qB##P##_3); \
      int tA = eA##P + 16, tB = eB##P + 16; \
      if (__builtin_expect(tA < reA##P || tB < reB##P, 0)){ \
        do { \
          const int sa0 = (tA     < reA##P) ? csr[min(tA    , EN-1)] : NN; \
          const int sa1 = (tA + 4 < reA##P) ? csr[min(tA + 4, EN-1)] : NN; \
          const int sb0 = (tB     < reB##P) ? csr[min(tB    , EN-1)] : NN; \
          const int sb1 = (tB + 4 < reB##P) ? csr[min(tB + 4, EN-1)] : NN; \
          uint4 xa0 = *(const uint4*)(hcol + (size_t)sa0*CN); \
          uint4 xa1 = *(const uint4*)(hcol + (size_t)sa1*CN); \
          uint4 xb0 = *(const uint4*)(hcol + (size_t)sb0*CN); \
          uint4 xb1 = *(const uint4*)(hcol + (size_t)sb1*CN); \
          unp_add(accA,xa0); unp_add(accA,xa1); unp_add(accB,xb0); unp_add(accB,xb1); \
          tA += 8; tB += 8; \
        } while (tA < reA##P || tB < reB##P); \
      } \
      _Pragma("unroll") \
      for (int j=0;j<8;++j){ \
        accA[j] += __shfl_xor(accA[j],16); accA[j] += __shfl_xor(accA[j],32); \
        accB[j] += __shfl_xor(accB[j],16); accB[j] += __shfl_xor(accB[j],32); \
      } \
      const float invA = 1.0f / fmaxf((float)dgA##P, 1.0f); \
      const float invB = 1.0f / fmaxf((float)dgB##P, 1.0f); \
      if (g==0){ \
        u16 ta[8], tb[8]; \
        _Pragma("unroll") \
        for (int j=0;j<8;++j){ ta[j]=f2bf(accA[j]*invA); tb[j]=f2bf(accB[j]*invB); } \
        *(uint4*)&sv[(IA)*136 + c16*8] = *(const uint4*)ta; \
        *(uint4*)&sv[(IB)*136 + c16*8] = *(const uint4*)tb; \
      } \
    }

    LOAD_IDX(0, nb,      nb + 4)
    LOAD_ROWS(0)
    LOAD_IDX(1, nb + 8,  nb + 12)
    FINISH(0, w, w + 4)
    LOAD_ROWS(1)
    LOAD_IDX(2, nb + 16, nb + 20)
    FINISH(1, 8 + w, 12 + w)
    LOAD_ROWS(2)
    LOAD_IDX(3, nb + 24, nb + 28)
    FINISH(2, 16 + w, 20 + w)
    LOAD_ROWS(3)
    FINISH(3, 24 + w, 28 + w)
#undef LOAD_IDX
#undef LOAD_ROWS
#undef FINISH
  }
  __syncthreads();

  // Phase B: acc = local (sv @ lin_w^T, K=128) + spec (U16 @ ohatT^T, K=64)
  const int rt = w&1, cb = w>>1;
  const int lo16 = lane & 15, qd = (lane>>4)<<3;
  f32x4 acc[4] = {};
  #pragma unroll
  for (int ks=0; ks<4; ++ks){
    short8 af = *(const short8*)&sv[(rt*16 + lo16)*136 + ks*32 + qd];
    #pragma unroll
    for (int c4=0; c4<4; ++c4){
      const short8 bf = *(const short8*)(wsw + ((size_t)((cb*4+c4)*4+ks)*64 + lane)*8);
      acc[c4] = __builtin_amdgcn_mfma_f32_16x16x32_bf16(af, bf, acc[c4], 0, 0, 0);
    }
  }
  {
    const int b = (int)(n0 >> 11);                              // node block -> batch
    const u16* Au = U16  + ((size_t)(n0 + rt*16 + lo16))*MN + qd;
    const u16* Bu = ohatT + ((size_t)(b*CN + cb*64 + lo16))*MN + qd;
    #pragma unroll
    for (int ks=0; ks<2; ++ks){
      short8 af = *(const short8*)(Au + ks*32);
      #pragma unroll
      for (int c4=0; c4<4; ++c4){
        short8 bf = *(const short8*)(Bu + (size_t)c4*16*MN + ks*32);
        acc[c4] = __builtin_amdgcn_mfma_f32_16x16x32_bf16(af, bf, acc[c4], 0, 0, 0);
      }
    }
  }
  #pragma unroll
  for (int c4=0; c4<4; ++c4){
    int col = cb*64 + c4*16 + lo16;
    int rb = rt*16 + ((lane>>4)<<2);
    #pragma unroll
    for (int r=0; r<4; ++r) sx16[(rb+r)*132 + col] = f2bf(acc[c4][r]);
  }
  __syncthreads();

  // Phase C: x = h + (spec+local) + bias; LayerNorm; exact GELU
  float2 lb    = *(const float2*)(lin_b  + 2*lane);
  float2 lg    = *(const float2*)(ln_g   + 2*lane);
  float2 lbe   = *(const float2*)(ln_beta+ 2*lane);
  for (int r=0; r<8; ++r){
    int i = r*4 + w;
    size_t base = (n0 + i)*CN + 2*lane;
    u32 hA = *(const u32*)(h16 + base);
    u32 lA = *(const u32*)&sx16[i*132 + 2*lane];
    float x0 = bf2f((u16)(hA&0xffffu)) + bf2f((u16)(lA&0xffffu)) + lb.x;
    float x1 = bf2f((u16)(hA>>16))     + bf2f((u16)(lA>>16))     + lb.y;
    float s  = x0 + x1;
    float ss = fmaf(x0,x0, x1*x1);
    #pragma unroll
    for (int d=1; d<64; d<<=1){ s += __shfl_xor(s,d); ss += __shfl_xor(ss,d); }
    float mu  = s*(1.0f/128.0f);
    float var = ss*(1.0f/128.0f) - mu*mu;
    float rstd = rsqrtf(var + 1e-5f);
    float xn0 = (x0-mu)*rstd*lg.x + lbe.x;
    float xn1 = (x1-mu)*rstd*lg.y + lbe.y;
    float2 st;
    st.x = 0.5f*xn0*(1.0f + erff(xn0*0.70710678118654752f));
    st.y = 0.5f*xn1*(1.0f + erff(xn1*0.70710678118654752f));
    *(float2*)(out + base) = st;
  }
}

extern "C" void kernel_launch(void* const* d_in, const int* in_sizes, int n_in,
                              void* d_out, int out_size, void* d_ws, size_t ws_size,
                              hipStream_t stream) {
  const float* h      = (const float*)d_in[0];
  const float* U      = (const float*)d_in[1];
  const float* W      = (const float*)d_in[2];
  const float* lin_w  = (const float*)d_in[3];
  const float* lin_b  = (const float*)d_in[4];
  const float* ln_g   = (const float*)d_in[5];
  const float* ln_b2  = (const float*)d_in[6];
  const int* ei       = (const int*)d_in[7];
  const int* src = ei;
  const int* dst = ei + EN;
  float* out = (float*)d_out;

  char* wp = (char*)d_ws;
  float* hp     = (float*)wp; wp += (size_t)8*BN*MN*CN*sizeof(float);    // 16.8 MB
  u16*   ohatT  = (u16*)wp;   wp += (size_t)BN*CN*MN*sizeof(u16);        // 1.05 MB
  u16*   h16    = (u16*)wp;   wp += (size_t)(NN+1)*CN*sizeof(u16);       // 33.5 MB (+zero row)
  u16*   ht16   = (u16*)wp;   wp += (size_t)BN*CN*NPGN*sizeof(u16);      // 33.5 MB
  u16*   U16b   = (u16*)wp;   wp += (size_t)BN*NPGN*MN*sizeof(u16);      // 16.8 MB
  u16*   Ut16   = (u16*)wp;   wp += (size_t)BN*MN*NPGN*sizeof(u16);      // 16.8 MB
  u16*   wsw    = (u16*)wp;   wp += (size_t)CN*CN*sizeof(u16);           // 32 KB
  u16*   WT16   = (u16*)wp;   wp += (size_t)MN*CN*CN*sizeof(u16);        // 2.1 MB
  int*   deg    = (int*)wp;   wp += (size_t)NN*sizeof(int);
  int*   rowst  = (int*)wp;   wp += (size_t)NN*sizeof(int);
  int*   cursor = (int*)wp;   wp += (size_t)NN*sizeof(int);
  int*   csr    = (int*)wp;   wp += (size_t)EN*sizeof(int);              // 4.2 MB
  int*   bsum   = (int*)wp;   wp += 512*sizeof(int);

  hipMemsetAsync(deg,    0, (size_t)NN*sizeof(int), stream);
  hipMemsetAsync(cursor, 0, (size_t)NN*sizeof(int), stream);
  hipMemsetAsync(h16 + (size_t)NN*CN, 0, CN*sizeof(u16), stream);   // zero row

  k_front<<<7304, 256, 0, stream>>>(h, h16, ht16, U, U16b, Ut16, lin_w, wsw, W, WT16, dst, deg);
  k_scan1<<<NN/512, 512, 0, stream>>>(deg, rowst, bsum);
  k_scan23<<<NN/256, 256, 0, stream>>>(rowst, bsum);
  k_mid<<<1024 + EN/256, 256, 0, stream>>>(Ut16, ht16, hp, src, dst, rowst, cursor, csr);
  k_ohat<<<MN*4, 256, 0, stream>>>(hp, WT16, ohatT);
  k_localep<<<NN/32, 256, 0, stream>>>(h16, U16b, ohatT, wsw, rowst, deg, csr,
                                       lin_b, ln_g, ln_b2, out);
}

// Round 12
// 368.862 us; speedup vs baseline: 1.1593x; 1.1593x over previous
//
#include <hip/hip_runtime.h>
#include <math.h>

#define NN   131072
#define CN   128
#define BN   64
#define NPGN 2048
#define MN   64
#define EN   1048576

typedef unsigned short u16;
typedef unsigned int   u32;
typedef __attribute__((ext_vector_type(8))) short short8;
typedef __attribute__((ext_vector_type(4))) float f32x4;

__device__ __forceinline__ float bf2f(u16 u){ return __uint_as_float(((u32)u)<<16); }
__device__ __forceinline__ u16 f2bf(float f){
  u32 x = __float_as_uint(f);
  return (u16)((x + 0x7fffu + ((x>>16)&1u)) >> 16);
}

// ---------------- graph scans ----------------
__global__ void k_scan1(const int* __restrict__ deg, int* __restrict__ rowst, int* __restrict__ bsum){
  __shared__ int s[512];
  const int t = threadIdx.x;
  const int i = blockIdx.x*512 + t;
  int v = deg[i];
  s[t] = v;
  __syncthreads();
  for (int off=1; off<512; off<<=1){
    int a = (t>=off) ? s[t-off] : 0;
    __syncthreads();
    s[t] += a;
    __syncthreads();
  }
  rowst[i] = s[t] - v;
  if (t==511) bsum[blockIdx.x] = s[511];
}

// merged scan2+scan3: each block adds sum(bsum[0 .. bid/2)) to its rowst slice
__global__ void k_scan23(int* __restrict__ rowst, const int* __restrict__ bsum){
  __shared__ int sred[4];
  const int t = threadIdx.x;
  const int gidx = blockIdx.x >> 1;      // all i in this block share i>>9 == bid>>1
  int v = (t < gidx) ? bsum[t] : 0;
  #pragma unroll
  for (int d=1; d<64; d<<=1) v += __shfl_xor(v, d);
  if ((t&63)==0) sred[t>>6] = v;
  __syncthreads();
  int tot = sred[0]+sred[1]+sred[2]+sred[3];
  int i = blockIdx.x*256 + t;
  rowst[i] += tot;
}

// ---------------- front: prep_h + prep_U + prepw + prepWT + count (independent) ----------------
__global__ __launch_bounds__(256) void k_front(
    const float* __restrict__ h, u16* __restrict__ h16, u16* __restrict__ ht16,
    const float* __restrict__ U, u16* __restrict__ U16, u16* __restrict__ Ut16,
    const float* __restrict__ lin_w, u16* __restrict__ wsw,
    const float* __restrict__ W, u16* __restrict__ WT16,
    const int* __restrict__ dst, int* __restrict__ deg){
  __shared__ u16 stu[CN*72];   // 18.4 KB union
  const int t = threadIdx.x;
  const int bid = blockIdx.x;

  if (bid < 2048){
    // ---- prep_h: tile = 64 n-rows x 128 c ----
    const int b = bid >> 5;
    const int n0 = (bid & 31)*64;
    const float* srcb = h + ((size_t)b*NPGN + n0)*CN;
    u16* natb = h16 + ((size_t)b*NPGN + n0)*CN;
    #pragma unroll
    for (int j=0;j<8;++j){
      int fidx = (j*256+t)*4;
      int r = fidx>>7, c = fidx&127;
      float4 v = *(const float4*)(srcb + fidx);
      u16 q0=f2bf(v.x), q1=f2bf(v.y), q2=f2bf(v.z), q3=f2bf(v.w);
      ushort4 nv; nv.x=q0; nv.y=q1; nv.z=q2; nv.w=q3;
      *(ushort4*)(natb + fidx) = nv;
      stu[(c+0)*72 + r] = q0; stu[(c+1)*72 + r] = q1;
      stu[(c+2)*72 + r] = q2; stu[(c+3)*72 + r] = q3;
    }
    __syncthreads();
    #pragma unroll
    for (int j=0;j<4;++j){
      int oidx = (j*256+t)*8;
      int c = oidx>>6, nn = oidx&63;
      uint4 v = *(const uint4*)&stu[c*72 + nn];
      *(uint4*)(ht16 + ((size_t)b*CN + c)*NPGN + n0 + nn) = v;
    }
  } else if (bid < 3072){
    // ---- prep_U: tile = 128 n-rows x 64 m ----
    const int ub = bid - 2048;
    const int b = ub >> 4;
    const int n0 = (ub & 15)*128;
    const float* srcb = U + ((size_t)b*NPGN + n0)*MN;
    u16* natb = U16 + ((size_t)b*NPGN + n0)*MN;
    #pragma unroll
    for (int j=0;j<8;++j){
      int fidx = (j*256+t)*4;
      int r = fidx>>6, mm = fidx&63;
      float4 v = *(const float4*)(srcb + fidx);
      u16 q0=f2bf(v.x), q1=f2bf(v.y), q2=f2bf(v.z), q3=f2bf(v.w);
      ushort4 nv; nv.x=q0; nv.y=q1; nv.z=q2; nv.w=q3;
      *(ushort4*)(natb + fidx) = nv;
      stu[(mm+0)*136 + r] = q0; stu[(mm+1)*136 + r] = q1;
      stu[(mm+2)*136 + r] = q2; stu[(mm+3)*136 + r] = q3;
    }
    __syncthreads();
    #pragma unroll
    for (int j=0;j<4;++j){
      int oidx = (j*256+t)*8;
      int mm = oidx>>7, nn = oidx&127;
      uint4 v = *(const uint4*)&stu[mm*136 + nn];
      *(uint4*)(Ut16 + ((size_t)b*MN + mm)*NPGN + n0 + nn) = v;
    }
  } else if (bid < 3080){
    // ---- prepw: B-fragment-swizzled bf16 lin_w ----
    int tid = (bid - 3072)*256 + t;   // 2048 total
    int g = tid >> 6, L = tid & 63;
    int ct = g >> 2, ks = g & 3;
    int o = L & 15, q = L >> 4;
    const float* srcp = lin_w + (ct*16+o)*CN + ks*32 + q*8;
    u16 tmp[8];
    #pragma unroll
    for (int j=0;j<8;++j) tmp[j] = f2bf(srcp[j]);
    *(uint4*)(wsw + (size_t)tid*8) = *(const uint4*)tmp;
  } else if (bid < 3208){
    // ---- prepWT half-tile: W[m][c][o] -> WT16[m][o][c], c-half per block ----
    const int mb = bid - 3080;         // 0..127
    const int m = mb >> 1, c0 = (mb & 1)*64;
    const float* Wm = W + (size_t)m*CN*CN + (size_t)c0*CN;
    #pragma unroll
    for (int it=0; it<8; ++it){
      int flat = (it*256 + t)*4;       // over 64c x 128o
      int c = flat >> 7, o = flat & 127;
      float4 v = *(const float4*)(Wm + flat);
      stu[(o+0)*68 + c] = f2bf(v.x);
      stu[(o+1)*68 + c] = f2bf(v.y);
      stu[(o+2)*68 + c] = f2bf(v.z);
      stu[(o+3)*68 + c] = f2bf(v.w);
    }
    __syncthreads();
    u16* dstm = WT16 + (size_t)m*CN*CN + c0;
    #pragma unroll
    for (int it=0; it<4; ++it){
      int oidx = (it*256 + t)*8;       // over 128o x 64c
      int o = oidx >> 6, cc = oidx & 63;
      uint4 v = *(const uint4*)&stu[o*68 + cc];
      *(uint4*)(dstm + (size_t)o*CN + cc) = v;
    }
  } else {
    // ---- count ----
    int e = (bid - 3208)*256 + t;
    atomicAdd(&deg[dst[e]], 1);
  }
}

// ---------------- mid: h_hat MFMA partials + csr fill (independent) ----------------
__global__ __launch_bounds__(256) void k_mid(
    const u16* __restrict__ Ut16, const u16* __restrict__ ht16, float* __restrict__ hp,
    const int* __restrict__ src, const int* __restrict__ dst,
    const int* __restrict__ rowst, int* __restrict__ cursor, int* __restrict__ csr){
  const int bid = blockIdx.x;
  if (bid < 1024){
    // hhat: hp[q][b][m][c], K-chunk 256, c-half per block
    const int t = threadIdx.x;
    const int L = t & 63, w = t >> 6;
    const int b  = bid >> 4;
    const int q  = (bid >> 1) & 7;
    const int ch = bid & 1;
    const int lo = L & 15, qd = (L >> 4) << 3;
    f32x4 acc[4] = {};
    const u16* Arow  = Ut16 + ((size_t)(b*MN + w*16 + lo))*NPGN + q*256 + qd;
    const u16* Bbase = ht16 + ((size_t)(b*CN + ch*64 + lo))*NPGN + q*256 + qd;
    #pragma unroll
    for (int ks=0; ks<8; ++ks){
      short8 af = *(const short8*)(Arow + ks*32);
      #pragma unroll
      for (int ct=0; ct<4; ++ct){
        short8 bf = *(const short8*)(Bbase + (size_t)ct*16*NPGN + ks*32);
        acc[ct] = __builtin_amdgcn_mfma_f32_16x16x32_bf16(af, bf, acc[ct], 0, 0, 0);
      }
    }
    const int rb = w*16 + ((L>>4)<<2);
    float* dstb = hp + ((size_t)q*BN + b)*MN*CN;
    #pragma unroll
    for (int ct=0; ct<4; ++ct)
      #pragma unroll
      for (int r=0; r<4; ++r)
        dstb[(size_t)(rb+r)*CN + ch*64 + ct*16 + lo] = acc[ct][r];
  } else {
    // fill csr
    int e = (bid - 1024)*256 + threadIdx.x;
    int d = dst[e];
    int p = atomicAdd(&cursor[d], 1);
    csr[rowst[d] + p] = src[e];
  }
}

// ---------------- out_hat (MFMA): ohatT[b][o][m] = bf16( sum_c hh[b,c]*W[m,c,o] ) ----------------
__global__ __launch_bounds__(256) void k_ohat(const float* __restrict__ hp,
                                              const u16* __restrict__ WT16,
                                              u16* __restrict__ ohatT){
  __shared__ u16 shHi[16*132];   // 4.2 KB
  __shared__ u16 shLo[16*132];   // 4.2 KB
  const int t = threadIdx.x;
  const int m  = blockIdx.x >> 2;
  const int bq = blockIdx.x & 3;       // b-quarter: rows bq*16 .. bq*16+15

  {
    const int bl = t >> 4;             // 0..15
    const int c0 = (t & 15) * 8;       // 8 channels
    const size_t S = (size_t)BN*MN*CN;
    const float* base = hp + ((size_t)(bq*16 + bl)*MN + m)*CN + c0;
    float a[8] = {0,0,0,0,0,0,0,0};
    #pragma unroll
    for (int q=0; q<8; ++q){
      float4 v0 = *(const float4*)(base + q*S);
      float4 v1 = *(const float4*)(base + q*S + 4);
      a[0]+=v0.x; a[1]+=v0.y; a[2]+=v0.z; a[3]+=v0.w;
      a[4]+=v1.x; a[5]+=v1.y; a[6]+=v1.z; a[7]+=v1.w;
    }
    u16 hi[8], lo[8];
    #pragma unroll
    for (int j=0;j<8;++j){
      hi[j] = f2bf(a[j]);
      lo[j] = f2bf(a[j] - bf2f(hi[j]));
    }
    *(uint4*)&shHi[bl*132 + c0] = *(const uint4*)hi;
    *(uint4*)&shLo[bl*132 + c0] = *(const uint4*)lo;
  }
  __syncthreads();

  const int L = t & 63, w = t >> 6;
  const int lo16 = L & 15, qd = (L >> 4) << 3;
  const u16* WTm = WT16 + (size_t)m*CN*CN;
  f32x4 acc[2] = {};
  #pragma unroll
  for (int ks=0; ks<4; ++ks){
    short8 ah = *(const short8*)&shHi[lo16*132 + ks*32 + qd];
    short8 al = *(const short8*)&shLo[lo16*132 + ks*32 + qd];
    #pragma unroll
    for (int ot=0; ot<2; ++ot){
      short8 bf = *(const short8*)(WTm + (size_t)(w*32 + ot*16 + lo16)*CN + ks*32 + qd);
      acc[ot] = __builtin_amdgcn_mfma_f32_16x16x32_bf16(ah, bf, acc[ot], 0, 0, 0);
      acc[ot] = __builtin_amdgcn_mfma_f32_16x16x32_bf16(al, bf, acc[ot], 0, 0, 0);
    }
  }
  const int rb = (L>>4)<<2;
  #pragma unroll
  for (int ot=0; ot<2; ++ot){
    #pragma unroll
    for (int r=0; r<4; ++r){
      int b = bq*16 + rb + r;
      int o = w*32 + ot*16 + lo16;
      ohatT[((size_t)b*CN + o)*MN + m] = f2bf(acc[ot][r]);
    }
  }
}

// ---------------- fused: gather-mean + (local+spec) MFMA + LN + GELU ----------------
__device__ __forceinline__ void unp_add(float* a, uint4 p){
  a[0]+=__uint_as_float(p.x<<16); a[1]+=__uint_as_float(p.x&0xffff0000u);
  a[2]+=__uint_as_float(p.y<<16); a[3]+=__uint_as_float(p.y&0xffff0000u);
  a[4]+=__uint_as_float(p.z<<16); a[5]+=__uint_as_float(p.z&0xffff0000u);
  a[6]+=__uint_as_float(p.w<<16); a[7]+=__uint_as_float(p.w&0xffff0000u);
}

__global__ __launch_bounds__(256,5) void k_localep(
    const u16* __restrict__ h16, const u16* __restrict__ U16,
    const u16* __restrict__ ohatT, const u16* __restrict__ wsw,
    const int* __restrict__ rowst, const int* __restrict__ deg, const int* __restrict__ csr,
    const float* __restrict__ lin_b, const float* __restrict__ ln_g,
    const float* __restrict__ ln_beta, float* __restrict__ out){
  __shared__ u16 sv[32*136];     // 8.7 KB  mean-neighbor rows (bf16, pitch 136)
  __shared__ u16 sx16[32*132];   // 8.4 KB  local+spec result (bf16)
  const int t = threadIdx.x;
  const int w = t>>6, lane = t&63;
  const size_t n0 = (size_t)blockIdx.x*32;

  // Phase A (R8-validated, 90.6us): software-pipelined, manually-unrolled, named
  // scalars only. idx(p+1) loads issue while rows(p) are in flight / unpacking.
  // (256,5) is the validated optimum: (256,8) forces VGPR 48->32 + spill (R11).
  {
    const int g   = lane >> 4;    // edge slot 0..3
    const int c16 = lane & 15;    // channel group: channels c16*8 .. c16*8+7
    const u16* hcol = h16 + c16*8;
    const int nb = (int)n0 + w;

#define LOAD_IDX(P, NA, NB) \
    const int rsA##P = rowst[NA], dgA##P = deg[NA]; \
    const int rsB##P = rowst[NB], dgB##P = deg[NB]; \
    const int eA##P = rsA##P + g, eB##P = rsB##P + g; \
    const int reA##P = rsA##P + dgA##P, reB##P = rsB##P + dgB##P; \
    const int jA##P##_0 = csr[min(eA##P     , EN-1)]; \
    const int jA##P##_1 = csr[min(eA##P +  4, EN-1)]; \
    const int jA##P##_2 = csr[min(eA##P +  8, EN-1)]; \
    const int jA##P##_3 = csr[min(eA##P + 12, EN-1)]; \
    const int jB##P##_0 = csr[min(eB##P     , EN-1)]; \
    const int jB##P##_1 = csr[min(eB##P +  4, EN-1)]; \
    const int jB##P##_2 = csr[min(eB##P +  8, EN-1)]; \
    const int jB##P##_3 = csr[min(eB##P + 12, EN-1)];

#define LOAD_ROWS(P) \
    const uint4 qA##P##_0 = *(const uint4*)(hcol + (size_t)((eA##P      < reA##P) ? jA##P##_0 : NN)*CN); \
    const uint4 qA##P##_1 = *(const uint4*)(hcol + (size_t)((eA##P +  4 < reA##P) ? jA##P##_1 : NN)*CN); \
    const uint4 qA##P##_2 = *(const uint4*)(hcol + (size_t)((eA##P +  8 < reA##P) ? jA##P##_2 : NN)*CN); \
    const uint4 qA##P##_3 = *(const uint4*)(hcol + (size_t)((eA##P + 12 < reA##P) ? jA##P##_3 : NN)*CN); \
    const uint4 qB##P##_0 = *(const uint4*)(hcol + (size_t)((eB##P      < reB##P) ? jB##P##_0 : NN)*CN); \
    const uint4 qB##P##_1 = *(const uint4*)(hcol + (size_t)((eB##P +  4 < reB##P) ? jB##P##_1 : NN)*CN); \
    const uint4 qB##P##_2 = *(const uint4*)(hcol + (size_t)((eB##P +  8 < reB##P) ? jB##P##_2 : NN)*CN); \
    const uint4 qB##P##_3 = *(const uint4*)(hcol + (size_t)((eB##P + 12 < reB##P) ? jB##P##_3 : NN)*CN);

#define FINISH(P, IA, IB) \
    { \
      float accA[8]={0,0,0,0,0,0,0,0}, accB[8]={0,0,0,0,0,0,0,0}; \
      unp_add(accA,qA##P##_0); unp_add(accA,qA##P##_1); unp_add(accA,qA##P##_2); unp_add(accA,qA##P##_3); \
      unp_add(accB,qB##P##_0); unp_add(accB,qB##P##_1); unp_add(accB,qB##P##_2); unp_add(accB,qB##P##_3); \
      int tA = eA##P + 16, tB = eB##P + 16; \
      if (__builtin_expect(tA < reA##P || tB < reB##P, 0)){ \
        do { \
          const int sa0 = (tA     < reA##P) ? csr[min(tA    , EN-1)] : NN; \
          const int sa1 = (tA + 4 < reA##P) ? csr[min(tA + 4, EN-1)] : NN; \
          const int sb0 = (tB     < reB##P) ? csr[min(tB    , EN-1)] : NN; \
          const int sb1 = (tB + 4 < reB##P) ? csr[min(tB + 4, EN-1)] : NN; \
          uint4 xa0 = *(const uint4*)(hcol + (size_t)sa0*CN); \
          uint4 xa1 = *(const uint4*)(hcol + (size_t)sa1*CN); \
          uint4 xb0 = *(const uint4*)(hcol + (size_t)sb0*CN); \
          uint4 xb1 = *(const uint4*)(hcol + (size_t)sb1*CN); \
          unp_add(accA,xa0); unp_add(accA,xa1); unp_add(accB,xb0); unp_add(accB,xb1); \
          tA += 8; tB += 8; \
        } while (tA < reA##P || tB < reB##P); \
      } \
      _Pragma("unroll") \
      for (int j=0;j<8;++j){ \
        accA[j] += __shfl_xor(accA[j],16); accA[j] += __shfl_xor(accA[j],32); \
        accB[j] += __shfl_xor(accB[j],16); accB[j] += __shfl_xor(accB[j],32); \
      } \
      const float invA = 1.0f / fmaxf((float)dgA##P, 1.0f); \
      const float invB = 1.0f / fmaxf((float)dgB##P, 1.0f); \
      if (g==0){ \
        u16 ta[8], tb[8]; \
        _Pragma("unroll") \
        for (int j=0;j<8;++j){ ta[j]=f2bf(accA[j]*invA); tb[j]=f2bf(accB[j]*invB); } \
        *(uint4*)&sv[(IA)*136 + c16*8] = *(const uint4*)ta; \
        *(uint4*)&sv[(IB)*136 + c16*8] = *(const uint4*)tb; \
      } \
    }

    LOAD_IDX(0, nb,      nb + 4)
    LOAD_ROWS(0)
    LOAD_IDX(1, nb + 8,  nb + 12)
    FINISH(0, w, w + 4)
    LOAD_ROWS(1)
    LOAD_IDX(2, nb + 16, nb + 20)
    FINISH(1, 8 + w, 12 + w)
    LOAD_ROWS(2)
    LOAD_IDX(3, nb + 24, nb + 28)
    FINISH(2, 16 + w, 20 + w)
    LOAD_ROWS(3)
    FINISH(3, 24 + w, 28 + w)
#undef LOAD_IDX
#undef LOAD_ROWS
#undef FINISH
  }
  __syncthreads();

  // Phase B: acc = local (sv @ lin_w^T, K=128) + spec (U16 @ ohatT^T, K=64)
  const int rt = w&1, cb = w>>1;
  const int lo16 = lane & 15, qd = (lane>>4)<<3;
  f32x4 acc[4] = {};
  #pragma unroll
  for (int ks=0; ks<4; ++ks){
    short8 af = *(const short8*)&sv[(rt*16 + lo16)*136 + ks*32 + qd];
    #pragma unroll
    for (int c4=0; c4<4; ++c4){
      const short8 bf = *(const short8*)(wsw + ((size_t)((cb*4+c4)*4+ks)*64 + lane)*8);
      acc[c4] = __builtin_amdgcn_mfma_f32_16x16x32_bf16(af, bf, acc[c4], 0, 0, 0);
    }
  }
  {
    const int b = (int)(n0 >> 11);                              // node block -> batch
    const u16* Au = U16  + ((size_t)(n0 + rt*16 + lo16))*MN + qd;
    const u16* Bu = ohatT + ((size_t)(b*CN + cb*64 + lo16))*MN + qd;
    #pragma unroll
    for (int ks=0; ks<2; ++ks){
      short8 af = *(const short8*)(Au + ks*32);
      #pragma unroll
      for (int c4=0; c4<4; ++c4){
        short8 bf = *(const short8*)(Bu + (size_t)c4*16*MN + ks*32);
        acc[c4] = __builtin_amdgcn_mfma_f32_16x16x32_bf16(af, bf, acc[c4], 0, 0, 0);
      }
    }
  }
  #pragma unroll
  for (int c4=0; c4<4; ++c4){
    int col = cb*64 + c4*16 + lo16;
    int rb = rt*16 + ((lane>>4)<<2);
    #pragma unroll
    for (int r=0; r<4; ++r) sx16[(rb+r)*132 + col] = f2bf(acc[c4][r]);
  }
  __syncthreads();

  // Phase C: x = h + (spec+local) + bias; LayerNorm; exact GELU
  float2 lb    = *(const float2*)(lin_b  + 2*lane);
  float2 lg    = *(const float2*)(ln_g   + 2*lane);
  float2 lbe   = *(const float2*)(ln_beta+ 2*lane);
  for (int r=0; r<8; ++r){
    int i = r*4 + w;
    size_t base = (n0 + i)*CN + 2*lane;
    u32 hA = *(const u32*)(h16 + base);
    u32 lA = *(const u32*)&sx16[i*132 + 2*lane];
    float x0 = bf2f((u16)(hA&0xffffu)) + bf2f((u16)(lA&0xffffu)) + lb.x;
    float x1 = bf2f((u16)(hA>>16))     + bf2f((u16)(lA>>16))     + lb.y;
    float s  = x0 + x1;
    float ss = fmaf(x0,x0, x1*x1);
    #pragma unroll
    for (int d=1; d<64; d<<=1){ s += __shfl_xor(s,d); ss += __shfl_xor(ss,d); }
    float mu  = s*(1.0f/128.0f);
    float var = ss*(1.0f/128.0f) - mu*mu;
    float rstd = rsqrtf(var + 1e-5f);
    float xn0 = (x0-mu)*rstd*lg.x + lbe.x;
    float xn1 = (x1-mu)*rstd*lg.y + lbe.y;
    float2 st;
    st.x = 0.5f*xn0*(1.0f + erff(xn0*0.70710678118654752f));
    st.y = 0.5f*xn1*(1.0f + erff(xn1*0.70710678118654752f));
    *(float2*)(out + base) = st;
  }
}

extern "C" void kernel_launch(void* const* d_in, const int* in_sizes, int n_in,
                              void* d_out, int out_size, void* d_ws, size_t ws_size,
                              hipStream_t stream) {
  const float* h      = (const float*)d_in[0];
  const float* U      = (const float*)d_in[1];
  const float* W      = (const float*)d_in[2];
  const float* lin_w  = (const float*)d_in[3];
  const float* lin_b  = (const float*)d_in[4];
  const float* ln_g   = (const float*)d_in[5];
  const float* ln_b2  = (const float*)d_in[6];
  const int* ei       = (const int*)d_in[7];
  const int* src = ei;
  const int* dst = ei + EN;
  float* out = (float*)d_out;

  char* wp = (char*)d_ws;
  float* hp     = (float*)wp; wp += (size_t)8*BN*MN*CN*sizeof(float);    // 16.8 MB
  u16*   ohatT  = (u16*)wp;   wp += (size_t)BN*CN*MN*sizeof(u16);        // 1.05 MB
  u16*   h16    = (u16*)wp;   wp += (size_t)(NN+1)*CN*sizeof(u16);       // 33.5 MB (+zero row)
  u16*   ht16   = (u16*)wp;   wp += (size_t)BN*CN*NPGN*sizeof(u16);      // 33.5 MB
  u16*   U16b   = (u16*)wp;   wp += (size_t)BN*NPGN*MN*sizeof(u16);      // 16.8 MB
  u16*   Ut16   = (u16*)wp;   wp += (size_t)BN*MN*NPGN*sizeof(u16);      // 16.8 MB
  u16*   wsw    = (u16*)wp;   wp += (size_t)CN*CN*sizeof(u16);           // 32 KB
  u16*   WT16   = (u16*)wp;   wp += (size_t)MN*CN*CN*sizeof(u16);        // 2.1 MB
  int*   deg    = (int*)wp;   wp += (size_t)NN*sizeof(int);
  int*   rowst  = (int*)wp;   wp += (size_t)NN*sizeof(int);
  int*   cursor = (int*)wp;   wp += (size_t)NN*sizeof(int);
  int*   csr    = (int*)wp;   wp += (size_t)EN*sizeof(int);              // 4.2 MB
  int*   bsum   = (int*)wp;   wp += 512*sizeof(int);

  hipMemsetAsync(deg,    0, (size_t)NN*sizeof(int), stream);
  hipMemsetAsync(cursor, 0, (size_t)NN*sizeof(int), stream);
  hipMemsetAsync(h16 + (size_t)NN*CN, 0, CN*sizeof(u16), stream);   // zero row

  k_front<<<7304, 256, 0, stream>>>(h, h16, ht16, U, U16b, Ut16, lin_w, wsw, W, WT16, dst, deg);
  k_scan1<<<NN/512, 512, 0, stream>>>(deg, rowst, bsum);
  k_scan23<<<NN/256, 256, 0, stream>>>(rowst, bsum);
  k_mid<<<1024 + EN/256, 256, 0, stream>>>(Ut16, ht16, hp, src, dst, rowst, cursor, csr);
  k_ohat<<<MN*4, 256, 0, stream>>>(hp, WT16, ohatT);
  k_localep<<<NN/32, 256, 0, stream>>>(h16, U16b, ohatT, wsw, rowst, deg, csr,
                                       lin_b, ln_g, ln_b2, out);
}